// Round 9
// baseline (199.071 us; speedup 1.0000x reference)
//
#include <hip/hip_runtime.h>
#include <cstddef>

// Problem constants
#define SS 64
#define NN 128
#define LL 10
#define DD 300
#define HH 150
#define HP 152           // H padded to 152 = 19*8 (16B-aligned float4 octets)
#define CC 16            // positions per block
#define RMAX (CC + LL - 1)   // 25 emb rows staged
#define JG 19            // j-octets
#define TG 13            // token-pairs

// Workspace layout (floats)
#define WS_W1P 0                 // D*HP = 45600
#define WS_BW  (DD*HP)           // 2*HP = 304 (b1 pad | W2 pad)
#define WS_DUMP (1u<<20)         // calibration dump region (4MB offset, 295MB used)

typedef float vf4 __attribute__((ext_vector_type(4)));

__device__ __forceinline__ void fma4(float4& a, float s, const float4 b) {
    a.x = fmaf(s, b.x, a.x);
    a.y = fmaf(s, b.y, a.y);
    a.z = fmaf(s, b.z, a.z);
    a.w = fmaf(s, b.w, a.w);
}

__device__ __forceinline__ void nt_store4(float* p, const float4 v) {
    vf4 t = {v.x, v.y, v.z, v.w};
    __builtin_nontemporal_store(t, (vf4*)p);
}

// ---------------- Kernel 0: pad weights ----------------
__global__ void pad_weights(const float* __restrict__ W1, const float* __restrict__ b1,
                            const float* __restrict__ W2, float* __restrict__ W1p,
                            float* __restrict__ bW) {
    int idx = blockIdx.x * 256 + threadIdx.x;
    if (idx < DD * HP) {
        int d = idx / HP, j = idx - d * HP;
        W1p[idx] = (j < HH) ? W1[d * HH + j] : 0.f;
    }
    if (idx < HP) {
        bW[idx] = (idx < HH) ? b1[idx] : 0.f;
    } else if (idx < 2 * HP) {
        int j = idx - HP;
        bW[idx] = (j < HH) ? W2[j] : 0.f;
    }
}

// ---------------- Fused kernel: gather + MLP + softmax + store ----------------
// R5 structure EXACTLY, plus one calibration pass: stream the same number of
// NT stores (zeros) into d_ws before the real output stores. A/B separates
// {timing floor} vs {store-BW cap} vs {non-store phases dominate}.
__global__ void k_fused(
        const int* __restrict__ tokens, const float* __restrict__ table,
        const float* __restrict__ W1p, const float* __restrict__ bW,
        const float* __restrict__ b2, float* __restrict__ out,
        float* __restrict__ wsdump)
{
    const int bid = blockIdx.x;          // s*8 + chunk
    const int s   = bid >> 3;
    const int i0  = (bid & 7) * CC;
    const int R   = min(RMAX, NN - i0);  // emb rows staged (25 or 16)

    __shared__ float le[RMAX][DD + 4];   // stride 304 floats
    __shared__ float lp[CC][LL][12];     // probs
    __shared__ float lpart[RMAX][20];    // 19 j-octet partials per token
    __shared__ float sc_l[RMAX];

    const int tid = threadIdx.x;
    const int tokbase = s * NN + i0;

    // ---- gather R emb rows (75 float4 each) ----
    for (int l = tid; l < R * 75; l += 256) {
        const int t = l / 75, q = l - t * 75;
        const int tok = tokens[tokbase + t];
        *(float4*)&le[t][q * 4] = *(const float4*)(table + (size_t)tok * DD + q * 4);
    }
    __syncthreads();

    // ---- MLP scores: 247 slots = 13 token-pairs x 19 j-octets ----
    if (tid < TG * JG) {
        const int tg = tid / JG;
        const int jg = tid - tg * JG;
        const int t0 = tg * 2;
        if (t0 < R) {
            const int t1 = (t0 + 1 < R) ? (t0 + 1) : t0;   // clamp, discard write
            const int j0 = jg * 8;
            const float* wp = W1p + j0;

            float4 a0l = {0,0,0,0}, a0h = {0,0,0,0}, a1l = {0,0,0,0}, a1h = {0,0,0,0};
            #pragma unroll 5
            for (int d = 0; d < DD; d += 4) {
                const float4 e0 = *(const float4*)&le[t0][d];
                const float4 e1 = *(const float4*)&le[t1][d];
                const float4 wa0 = *(const float4*)(wp + (size_t)(d + 0) * HP);
                const float4 wb0 = *(const float4*)(wp + (size_t)(d + 0) * HP + 4);
                const float4 wa1 = *(const float4*)(wp + (size_t)(d + 1) * HP);
                const float4 wb1 = *(const float4*)(wp + (size_t)(d + 1) * HP + 4);
                const float4 wa2 = *(const float4*)(wp + (size_t)(d + 2) * HP);
                const float4 wb2 = *(const float4*)(wp + (size_t)(d + 2) * HP + 4);
                const float4 wa3 = *(const float4*)(wp + (size_t)(d + 3) * HP);
                const float4 wb3 = *(const float4*)(wp + (size_t)(d + 3) * HP + 4);
                fma4(a0l, e0.x, wa0); fma4(a0h, e0.x, wb0);
                fma4(a0l, e0.y, wa1); fma4(a0h, e0.y, wb1);
                fma4(a0l, e0.z, wa2); fma4(a0h, e0.z, wb2);
                fma4(a0l, e0.w, wa3); fma4(a0h, e0.w, wb3);
                fma4(a1l, e1.x, wa0); fma4(a1h, e1.x, wb0);
                fma4(a1l, e1.y, wa1); fma4(a1h, e1.y, wb1);
                fma4(a1l, e1.z, wa2); fma4(a1h, e1.z, wb2);
                fma4(a1l, e1.w, wa3); fma4(a1h, e1.w, wb3);
            }
            const float4 bl = *(const float4*)(bW + j0);
            const float4 bh = *(const float4*)(bW + j0 + 4);
            const float4 vl = *(const float4*)(bW + HP + j0);
            const float4 vh = *(const float4*)(bW + HP + j0 + 4);

            #define RELD(A, B, V) (fmaxf((A).x + (B).x, 0.f) * (V).x + \
                                   fmaxf((A).y + (B).y, 0.f) * (V).y + \
                                   fmaxf((A).z + (B).z, 0.f) * (V).z + \
                                   fmaxf((A).w + (B).w, 0.f) * (V).w)
            lpart[t0][jg] = RELD(a0l, bl, vl) + RELD(a0h, bh, vh);
            if (t0 + 1 < R) lpart[t0 + 1][jg] = RELD(a1l, bl, vl) + RELD(a1h, bh, vh);
            #undef RELD
        }
    }
    __syncthreads();

    // ---- reduce 19 partials per token ----
    if (tid < R) {
        float sum = 0.f;
        #pragma unroll
        for (int jg = 0; jg < JG; ++jg) sum += lpart[tid][jg];
        sc_l[tid] = sum + b2[0];
    }
    __syncthreads();

    // ---- 160 softmax rows, 3-pass from LDS ----
    if (tid < CC * LL) {
        const int li = tid / LL, w = tid - li * LL;
        const int nk = min(LL, NN - (i0 + li));
        if (w < nk) {
            float m = -1e30f;
            for (int k = 0; k <= w; ++k) m = fmaxf(m, sc_l[li + k]);
            float sum = 0.f;
            for (int k = 0; k <= w; ++k) sum += __expf(sc_l[li + k] - m);
            const float inv = 1.f / sum;
            for (int k = 0; k <= w; ++k) lp[li][w][k] = __expf(sc_l[li + k] - m) * inv;
        }
    }
    __syncthreads();

    // ---- CALIBRATION PASS: same store count, pure zeros, into d_ws ----
    {
        float* dmp = wsdump + (size_t)bid * (CC * 9000);
        const float4 z = make_float4(0.f, 0.f, 0.f, 0.f);
        for (int o4 = tid; o4 < CC * 2250; o4 += 256) {
            nt_store4(dmp + (size_t)o4 * 4, z);
        }
    }

    // ---- real stores: 36000 float4 NT stores, coalesced ----
    float* dst = out + (size_t)tokbase * (LL * 3 * DD);
    for (int o4 = tid; o4 < CC * 2250; o4 += 256) {
        const int li = o4 / 2250;
        const int r  = o4 - li * 2250;
        const int w  = r / 225;
        const int c4 = r - w * 225;
        const int c  = c4 * 4;
        const int nk = min(LL, NN - (i0 + li));
        float4 v;
        if (w >= nk) {
            v = make_float4(0.f, 0.f, 0.f, 0.f);
        } else if (c < DD) {
            v = *(const float4*)&le[li][c];              // first = emb[i]
        } else if (c < 2 * DD) {
            v = *(const float4*)&le[li + w][c - DD];     // last = emb[i+w]
        } else {
            const int cc = c - 2 * DD;                   // head
            float4 a = make_float4(0.f, 0.f, 0.f, 0.f);
            for (int k = 0; k <= w; ++k) {
                fma4(a, lp[li][w][k], *(const float4*)&le[li + k][cc]);
            }
            v = a;
        }
        nt_store4(dst + (size_t)o4 * 4, v);
    }
}

// ---------------- Launch ----------------
extern "C" void kernel_launch(void* const* d_in, const int* in_sizes, int n_in,
                              void* d_out, int out_size, void* d_ws, size_t ws_size,
                              hipStream_t stream) {
    const int*   tokens = (const int*)d_in[0];
    const float* table  = (const float*)d_in[1];
    const float* W1     = (const float*)d_in[2];
    const float* b1     = (const float*)d_in[3];
    const float* W2     = (const float*)d_in[4];
    const float* b2     = (const float*)d_in[5];
    float* out = (float*)d_out;
    float* ws  = (float*)d_ws;

    float* W1p = ws + WS_W1P;
    float* bW  = ws + WS_BW;
    float* wsdump = ws + WS_DUMP;

    pad_weights<<<(DD * HP + 255) / 256, 256, 0, stream>>>(W1, b1, W2, W1p, bW);
    k_fused<<<SS * (NN / CC), 256, 0, stream>>>(tokens, table, W1p, bW, b2, out, wsdump);
}

// Round 10
// 125.566 us; speedup vs baseline: 1.5854x; 1.5854x over previous
//
#include <hip/hip_runtime.h>
#include <cstddef>

// Problem constants
#define SS 64
#define NN 128
#define LL 10
#define DD 300
#define HH 150
#define HP 152           // H padded to 152 = 19*8 (16B-aligned float4 octets)
#define CC 16            // positions per block
#define RMAX (CC + LL - 1)   // 25 emb rows staged
#define JG 19            // j-octets
#define TG 13            // token-pairs

// Workspace layout (floats)
#define WS_W1P 0                 // D*HP = 45600
#define WS_BW  (DD*HP)           // 2*HP = 304
#define WS_BLK (1 << 16)         // per-block staging start (65536 floats)
#define BLK_FLOATS 10240         // per-block staging: le 7600 | lp 1920 | pad
#define LE_FLOATS 7600           // RMAX * 304
#define LP_FLOATS 1920           // CC*LL*12

typedef float vf4 __attribute__((ext_vector_type(4)));

__device__ __forceinline__ void fma4(float4& a, float s, const float4 b) {
    a.x = fmaf(s, b.x, a.x);
    a.y = fmaf(s, b.y, a.y);
    a.z = fmaf(s, b.z, a.z);
    a.w = fmaf(s, b.w, a.w);
}

// ---------------- Kernel 0: pad weights ----------------
__global__ void pad_weights(const float* __restrict__ W1, const float* __restrict__ b1,
                            const float* __restrict__ W2, float* __restrict__ W1p,
                            float* __restrict__ bW) {
    int idx = blockIdx.x * 256 + threadIdx.x;
    if (idx < DD * HP) {
        int d = idx / HP, j = idx - d * HP;
        W1p[idx] = (j < HH) ? W1[d * HH + j] : 0.f;
    }
    if (idx < HP) {
        bW[idx] = (idx < HH) ? b1[idx] : 0.f;
    } else if (idx < 2 * HP) {
        int j = idx - HP;
        bW[idx] = (j < HH) ? W2[j] : 0.f;
    }
}

// ---------------- Kernel A: gather + MLP + softmax -> compact staging ----------
__global__ void k_stage(
        const int* __restrict__ tokens, const float* __restrict__ table,
        const float* __restrict__ W1p, const float* __restrict__ bW,
        const float* __restrict__ b2, float* __restrict__ blkws)
{
    const int bid = blockIdx.x;          // s*8 + chunk
    const int s   = bid >> 3;
    const int i0  = (bid & 7) * CC;
    const int R   = min(RMAX, NN - i0);

    __shared__ float le[RMAX][DD + 4];   // stride 304
    __shared__ float lp[CC][LL][12];
    __shared__ float lpart[RMAX][20];
    __shared__ float sc_l[RMAX];

    const int tid = threadIdx.x;
    const int tokbase = s * NN + i0;

    // ---- gather ----
    for (int l = tid; l < R * 75; l += 256) {
        const int t = l / 75, q = l - t * 75;
        const int tok = tokens[tokbase + t];
        *(float4*)&le[t][q * 4] = *(const float4*)(table + (size_t)tok * DD + q * 4);
    }
    __syncthreads();

    // ---- MLP: 247 slots = 13 token-pairs x 19 j-octets ----
    if (tid < TG * JG) {
        const int tg = tid / JG;
        const int jg = tid - tg * JG;
        const int t0 = tg * 2;
        if (t0 < R) {
            const int t1 = (t0 + 1 < R) ? (t0 + 1) : t0;
            const int j0 = jg * 8;
            const float* wp = W1p + j0;

            float4 a0l = {0,0,0,0}, a0h = {0,0,0,0}, a1l = {0,0,0,0}, a1h = {0,0,0,0};
            #pragma unroll 5
            for (int d = 0; d < DD; d += 4) {
                const float4 e0 = *(const float4*)&le[t0][d];
                const float4 e1 = *(const float4*)&le[t1][d];
                const float4 wa0 = *(const float4*)(wp + (size_t)(d + 0) * HP);
                const float4 wb0 = *(const float4*)(wp + (size_t)(d + 0) * HP + 4);
                const float4 wa1 = *(const float4*)(wp + (size_t)(d + 1) * HP);
                const float4 wb1 = *(const float4*)(wp + (size_t)(d + 1) * HP + 4);
                const float4 wa2 = *(const float4*)(wp + (size_t)(d + 2) * HP);
                const float4 wb2 = *(const float4*)(wp + (size_t)(d + 2) * HP + 4);
                const float4 wa3 = *(const float4*)(wp + (size_t)(d + 3) * HP);
                const float4 wb3 = *(const float4*)(wp + (size_t)(d + 3) * HP + 4);
                fma4(a0l, e0.x, wa0); fma4(a0h, e0.x, wb0);
                fma4(a0l, e0.y, wa1); fma4(a0h, e0.y, wb1);
                fma4(a0l, e0.z, wa2); fma4(a0h, e0.z, wb2);
                fma4(a0l, e0.w, wa3); fma4(a0h, e0.w, wb3);
                fma4(a1l, e1.x, wa0); fma4(a1h, e1.x, wb0);
                fma4(a1l, e1.y, wa1); fma4(a1h, e1.y, wb1);
                fma4(a1l, e1.z, wa2); fma4(a1h, e1.z, wb2);
                fma4(a1l, e1.w, wa3); fma4(a1h, e1.w, wb3);
            }
            const float4 bl = *(const float4*)(bW + j0);
            const float4 bh = *(const float4*)(bW + j0 + 4);
            const float4 vl = *(const float4*)(bW + HP + j0);
            const float4 vh = *(const float4*)(bW + HP + j0 + 4);

            #define RELD(A, B, V) (fmaxf((A).x + (B).x, 0.f) * (V).x + \
                                   fmaxf((A).y + (B).y, 0.f) * (V).y + \
                                   fmaxf((A).z + (B).z, 0.f) * (V).z + \
                                   fmaxf((A).w + (B).w, 0.f) * (V).w)
            lpart[t0][jg] = RELD(a0l, bl, vl) + RELD(a0h, bh, vh);
            if (t0 + 1 < R) lpart[t0 + 1][jg] = RELD(a1l, bl, vl) + RELD(a1h, bh, vh);
            #undef RELD
        }
    }
    __syncthreads();

    if (tid < R) {
        float sum = 0.f;
        #pragma unroll
        for (int jg = 0; jg < JG; ++jg) sum += lpart[tid][jg];
        sc_l[tid] = sum + b2[0];
    }
    __syncthreads();

    // ---- softmax ----
    if (tid < CC * LL) {
        const int li = tid / LL, w = tid - li * LL;
        const int nk = min(LL, NN - (i0 + li));
        if (w < nk) {
            float m = -1e30f;
            for (int k = 0; k <= w; ++k) m = fmaxf(m, sc_l[li + k]);
            float sum = 0.f;
            for (int k = 0; k <= w; ++k) sum += __expf(sc_l[li + k] - m);
            const float inv = 1.f / sum;
            for (int k = 0; k <= w; ++k) lp[li][w][k] = __expf(sc_l[li + k] - m) * inv;
        } else if (w < LL) {
            for (int k = 0; k < 12; ++k) lp[li][w][k] = 0.f;
        }
    }
    __syncthreads();

    // ---- dump le + lp to compact staging (L2-hot for kernel B) ----
    float* dst = blkws + (size_t)bid * BLK_FLOATS;
    const float* lef = &le[0][0];
    for (int l = tid; l < LE_FLOATS / 4; l += 256)
        *(float4*)(dst + l * 4) = *(const float4*)(lef + l * 4);
    const float* lpf = &lp[0][0][0];
    for (int l = tid; l < LP_FLOATS / 4; l += 256)
        *(float4*)(dst + LE_FLOATS + l * 4) = *(const float4*)(lpf + l * 4);
}

// ---------------- Kernel B: pure store streamer (cached stores) ----------------
__global__ void k_store(const float* __restrict__ blkws, float* __restrict__ out)
{
    const int bid = blockIdx.x;
    const int s   = bid >> 3;
    const int i0  = (bid & 7) * CC;

    __shared__ float le[RMAX][DD + 4];
    __shared__ float lp[CC][LL][12];

    const int tid = threadIdx.x;
    const float* src = blkws + (size_t)bid * BLK_FLOATS;

    float* lef = &le[0][0];
    for (int l = tid; l < LE_FLOATS / 4; l += 256)
        *(float4*)(lef + l * 4) = *(const float4*)(src + l * 4);
    float* lpf = &lp[0][0][0];
    for (int l = tid; l < LP_FLOATS / 4; l += 256)
        *(float4*)(lpf + l * 4) = *(const float4*)(src + LE_FLOATS + l * 4);
    __syncthreads();

    // flat coalesced store loop — REGULAR cached stores (fill-kernel arm)
    float* dst = out + (size_t)(s * NN + i0) * (LL * 3 * DD);
    for (int o4 = tid; o4 < CC * 2250; o4 += 256) {
        const int li = o4 / 2250;
        const int r  = o4 - li * 2250;
        const int w  = r / 225;
        const int c4 = r - w * 225;
        const int c  = c4 * 4;
        const int nk = min(LL, NN - (i0 + li));
        float4 v;
        if (w >= nk) {
            v = make_float4(0.f, 0.f, 0.f, 0.f);
        } else if (c < DD) {
            v = *(const float4*)&le[li][c];
        } else if (c < 2 * DD) {
            v = *(const float4*)&le[li + w][c - DD];
        } else {
            const int cc = c - 2 * DD;
            float4 a = make_float4(0.f, 0.f, 0.f, 0.f);
            for (int k = 0; k <= w; ++k) {
                fma4(a, lp[li][w][k], *(const float4*)&le[li + k][cc]);
            }
            v = a;
        }
        *(float4*)(dst + (size_t)o4 * 4) = v;
    }
}

// ---------------- Launch ----------------
extern "C" void kernel_launch(void* const* d_in, const int* in_sizes, int n_in,
                              void* d_out, int out_size, void* d_ws, size_t ws_size,
                              hipStream_t stream) {
    const int*   tokens = (const int*)d_in[0];
    const float* table  = (const float*)d_in[1];
    const float* W1     = (const float*)d_in[2];
    const float* b1     = (const float*)d_in[3];
    const float* W2     = (const float*)d_in[4];
    const float* b2     = (const float*)d_in[5];
    float* out = (float*)d_out;
    float* ws  = (float*)d_ws;

    float* W1p   = ws + WS_W1P;
    float* bW    = ws + WS_BW;
    float* blkws = ws + WS_BLK;

    pad_weights<<<(DD * HP + 255) / 256, 256, 0, stream>>>(W1, b1, W2, W1p, bW);
    k_stage<<<SS * (NN / CC), 256, 0, stream>>>(tokens, table, W1p, bW, b2, blkws);
    k_store<<<SS * (NN / CC), 256, 0, stream>>>(blkws, out);
}